// Round 5
// baseline (57.232 us; speedup 1.0000x reference)
//
#include <hip/hip_runtime.h>
#include <math.h>

#define BB 64
#define TT 512
#define CC 384
#define HH 64
#define MM (BB*TT)   // 32768 rows

// 0.125 (H^-0.5) * log2(e): scores hit hw exp2 directly; exp2(s*0.125*log2e)==exp(s*0.125)
#define QSCALE 0.18033688011112042f

typedef __attribute__((ext_vector_type(8))) short short8;
typedef __attribute__((ext_vector_type(4))) float f32x4;

__device__ __forceinline__ unsigned short f2bf(float f) {
    union { float f; unsigned int u; } x; x.f = f;
    unsigned int r = x.u + 0x7fff + ((x.u >> 16) & 1);   // RNE
    return (unsigned short)(r >> 16);
}

// ---------------- Kernel 0: W transpose + bf16 convert ----------------
// Wt[192][384] bf16: rows = output col n (0..63 Q, 64..127 K, 128..191 V).
// Q part pre-scaled by QSCALE.
__global__ __launch_bounds__(256) void prep_w(
    const float* __restrict__ Wq, const float* __restrict__ Wk,
    const float* __restrict__ Wv, unsigned short* __restrict__ Wt)
{
    __shared__ float t[64][65];
    const int which = blockIdx.x / 6;
    const int kt    = blockIdx.x % 6;
    const float* W = (which == 0) ? Wq : (which == 1) ? Wk : Wv;
    const float sc = (which == 0) ? QSCALE : 1.f;
    const int tid = threadIdx.x;
    #pragma unroll
    for (int i = 0; i < 16; i++) {
        int idx = tid + i * 256;
        int kl = idx >> 6, n = idx & 63;
        t[kl][n] = W[(size_t)(kt * 64 + kl) * HH + n];
    }
    __syncthreads();
    #pragma unroll
    for (int i = 0; i < 16; i++) {
        int idx = tid + i * 256;
        int nl = idx >> 6, kl = idx & 63;
        Wt[(size_t)(which * 64 + nl) * CC + kt * 64 + kl] = f2bf(t[kl][nl] * sc);
    }
}

// ---------------- Kernel 1: fused QKV projection, 32-row M-tiles ----------------
// 1024 blocks (4/CU), 25KB LDS, ~80 VGPR -> 16 waves/CU of latency-hiding TLP.
__global__ __launch_bounds__(256) void qkv_proj_mfma(
    const float* __restrict__ x, const unsigned short* __restrict__ Wt,
    const float* __restrict__ bq, const float* __restrict__ bk,
    const float* __restrict__ bv,
    unsigned short* __restrict__ qb, unsigned short* __restrict__ kb,
    unsigned short* __restrict__ vt)
{
    __shared__ unsigned short xs[32][CC + 8];   // [32][392] bf16, 25.1 KB
    const int tid  = threadIdx.x;
    const int w    = tid >> 6;
    const int lane = tid & 63;
    const int l15  = lane & 15;
    const int lg   = lane >> 4;
    const int rows0 = blockIdx.x * 32;

    #pragma unroll
    for (int kc = 0; kc < 6; kc++) {
        #pragma unroll
        for (int i = 0; i < 2; i++) {
            int idx = tid + i * 256;      // 512 = 32 rows x 16 float4
            int row = idx >> 4, j4 = idx & 15;
            const float4 xv = *reinterpret_cast<const float4*>(
                &x[(size_t)(rows0 + row) * CC + kc * 64 + j4 * 4]);
            ushort4 pk;
            pk.x = f2bf(xv.x); pk.y = f2bf(xv.y);
            pk.z = f2bf(xv.z); pk.w = f2bf(xv.w);
            *reinterpret_cast<ushort4*>(&xs[row][kc * 64 + j4 * 4]) = pk;
        }
    }
    __syncthreads();

    f32x4 acc[2][3];
    #pragma unroll
    for (int mi = 0; mi < 2; mi++)
        #pragma unroll
        for (int f = 0; f < 3; f++) acc[mi][f] = (f32x4){0.f, 0.f, 0.f, 0.f};

    #pragma unroll 4
    for (int ks = 0; ks < 12; ks++) {
        short8 afrag[2];
        #pragma unroll
        for (int mi = 0; mi < 2; mi++)
            afrag[mi] = *reinterpret_cast<const short8*>(
                &xs[mi * 16 + l15][ks * 32 + lg * 8]);
        #pragma unroll
        for (int f = 0; f < 3; f++) {
            const int n = w * 48 + f * 16 + l15;
            const short8 bfrag = *reinterpret_cast<const short8*>(
                &Wt[(size_t)n * CC + ks * 32 + lg * 8]);
            #pragma unroll
            for (int mi = 0; mi < 2; mi++)
                acc[mi][f] = __builtin_amdgcn_mfma_f32_16x16x32_bf16(
                    afrag[mi], bfrag, acc[mi][f], 0, 0, 0);
        }
    }

    // ---- epilogue. D: col = lane&15, row = (lane>>4)*4 + reg ----
    const int batch = rows0 >> 9;
    const int t0    = rows0 & 511;

    __syncthreads();   // all afrag reads done; reuse xs as transpose tile
    unsigned short (*L)[72] = reinterpret_cast<unsigned short (*)[72]>(&xs[0][0]);
    // L rows 0..31 = q tile [trow][c], rows 32..63 = k tile. (9.2KB of the 25.1KB)

    #pragma unroll
    for (int f = 0; f < 3; f++) {
        const int c = w * 48 + f * 16 + l15;   // 0..191
        if (c < 64) {
            const float bb = bq[c] * QSCALE;
            #pragma unroll
            for (int mi = 0; mi < 2; mi++)
                #pragma unroll
                for (int rr = 0; rr < 4; rr++)
                    L[mi * 16 + lg * 4 + rr][c] = f2bf(acc[mi][f][rr] + bb);
        } else if (c < 128) {
            const int ci = c - 64;
            const float bb = bk[ci];
            #pragma unroll
            for (int mi = 0; mi < 2; mi++)
                #pragma unroll
                for (int rr = 0; rr < 4; rr++)
                    L[32 + mi * 16 + lg * 4 + rr][ci] = f2bf(acc[mi][f][rr] + bb);
        } else {
            const int ci = c - 128;
            const float bb = bv[ci];
            #pragma unroll
            for (int mi = 0; mi < 2; mi++) {
                ushort4 pk;
                pk.x = f2bf(acc[mi][f][0] + bb);
                pk.y = f2bf(acc[mi][f][1] + bb);
                pk.z = f2bf(acc[mi][f][2] + bb);
                pk.w = f2bf(acc[mi][f][3] + bb);
                *reinterpret_cast<ushort4*>(
                    &vt[((size_t)batch * HH + ci) * TT + t0 + mi * 16 + lg * 4]) = pk;
            }
        }
    }
    __syncthreads();

    // packed store of q/k tiles: 64 rows x 64 cols bf16 = 512 x 16B
    #pragma unroll
    for (int i = 0; i < 2; i++) {
        int idx = tid + i * 256;          // 0..511
        int r = idx >> 3, c8 = idx & 7;
        const short8 val = *reinterpret_cast<const short8*>(&L[r][c8 * 8]);
        if (r < 32)
            *reinterpret_cast<short8*>(&qb[(size_t)(rows0 + r) * HH + c8 * 8]) = val;
        else
            *reinterpret_cast<short8*>(&kb[(size_t)(rows0 + r - 32) * HH + c8 * 8]) = val;
    }
}

// ---------------- Kernel 2: MFMA flash attention, tile-pipelined ----------------
// Fixed-max softmax (scores bounded by construction) -> tiles combine linearly,
// so iteration j runs QK(j) and PV(j-1): both MFMA clusters have operands
// loaded a FULL iteration earlier (K(j), V(j-1), P(j-1) all ready at iter top).
// exp->P-write chain of tile j overlaps PV(j-1). P double-buffered.
__global__ __launch_bounds__(64, 2) void attn_mfma(
    const unsigned short* __restrict__ q, const unsigned short* __restrict__ k,
    const unsigned short* __restrict__ vt, float* __restrict__ out)
{
    __shared__ unsigned short P[2][16][72];
    const int lane = threadIdx.x;
    const int l15  = lane & 15;
    const int lg   = lane >> 4;
    const int qs   = blockIdx.x >> 6;       // 0..31
    const int b    = blockIdx.x & 63;
    const int qr0  = b * TT + qs * 16;

    const unsigned short* __restrict__ kbase = k  + (size_t)b * TT * HH;
    const unsigned short* __restrict__ vbase = vt + (size_t)b * HH * TT;

    short8 aq[2];
    #pragma unroll
    for (int ks = 0; ks < 2; ks++)
        aq[ks] = *reinterpret_cast<const short8*>(
            &q[(size_t)(qr0 + l15) * HH + ks * 32 + lg * 8]);

    f32x4 accO[4];
    #pragma unroll
    for (int nf = 0; nf < 4; nf++) accO[nf] = (f32x4){0.f, 0.f, 0.f, 0.f};
    float lsum[4] = {0.f, 0.f, 0.f, 0.f};

    const int n = (qs >> 2) + 1;

#define LOADK(dst, j)                                                          \
    _Pragma("unroll")                                                          \
    for (int ks = 0; ks < 2; ks++)                                             \
        _Pragma("unroll")                                                      \
        for (int nf = 0; nf < 4; nf++)                                         \
            dst[ks][nf] = *reinterpret_cast<const short8*>(                    \
                &kbase[(size_t)((j) * 64 + nf * 16 + l15) * HH + ks * 32 + lg * 8]);
#define LOADV(dst, j)                                                          \
    _Pragma("unroll")                                                          \
    for (int ks = 0; ks < 2; ks++)                                             \
        _Pragma("unroll")                                                      \
        for (int nf = 0; nf < 4; nf++)                                         \
            dst[ks][nf] = *reinterpret_cast<const short8*>(                    \
                &vbase[(size_t)(nf * 16 + l15) * TT + (j) * 64 + ks * 32 + lg * 8]);

// QK on current kf into s
#define QKT(s, kf)                                                             \
    _Pragma("unroll")                                                          \
    for (int nf = 0; nf < 4; nf++) s[nf] = (f32x4){0.f, 0.f, 0.f, 0.f};        \
    _Pragma("unroll")                                                          \
    for (int ks = 0; ks < 2; ks++)                                             \
        _Pragma("unroll")                                                      \
        for (int nf = 0; nf < 4; nf++)                                         \
            s[nf] = __builtin_amdgcn_mfma_f32_16x16x32_bf16(aq[ks], kf[ks][nf], s[nf], 0, 0, 0);

// exp + mask (tile j) + lsum + P write into buffer pb
#define EXPP(s, j, pb)                                                         \
    {                                                                          \
        float p_[4][4];                                                        \
        if ((j) == n - 1) {                                                    \
            _Pragma("unroll")                                                  \
            for (int nf = 0; nf < 4; nf++)                                     \
                _Pragma("unroll")                                              \
                for (int rg = 0; rg < 4; rg++)                                 \
                    p_[nf][rg] = ((j) * 64 + nf * 16 + l15 > qs * 16 + lg * 4 + rg) \
                                 ? 0.f : exp2f(s[nf][rg]);                     \
        } else {                                                               \
            _Pragma("unroll")                                                  \
            for (int nf = 0; nf < 4; nf++)                                     \
                _Pragma("unroll")                                              \
                for (int rg = 0; rg < 4; rg++)                                 \
                    p_[nf][rg] = exp2f(s[nf][rg]);                             \
        }                                                                      \
        _Pragma("unroll")                                                      \
        for (int rg = 0; rg < 4; rg++)                                         \
            lsum[rg] += (p_[0][rg] + p_[1][rg]) + (p_[2][rg] + p_[3][rg]);     \
        _Pragma("unroll")                                                      \
        for (int nf = 0; nf < 4; nf++)                                         \
            _Pragma("unroll")                                                  \
            for (int rg = 0; rg < 4; rg++)                                     \
                P[pb][lg * 4 + rg][nf * 16 + l15] = f2bf(p_[nf][rg]);          \
    }

// PV on P buffer pb and vf
#define PVACC(pb, vf)                                                          \
    _Pragma("unroll")                                                          \
    for (int ks = 0; ks < 2; ks++) {                                           \
        const short8 pa = *reinterpret_cast<const short8*>(                    \
            &P[pb][l15][ks * 32 + lg * 8]);                                    \
        _Pragma("unroll")                                                      \
        for (int nf = 0; nf < 4; nf++)                                         \
            accO[nf] = __builtin_amdgcn_mfma_f32_16x16x32_bf16(                \
                pa, vf[ks][nf], accO[nf], 0, 0, 0);                            \
    }

    short8 kf[2][4], vf[2][4];

    // Prologue: tile 0
    LOADK(kf, 0);
    f32x4 s[4];
    QKT(s, kf);
    LOADV(vf, 0);
    if (n > 1) LOADK(kf, 1);     // K(1) for iter 1 (rows always in-bounds: tile<8)
    EXPP(s, 0, 0);

    // Steady: iter j computes QK(j) [kf=K(j)] and PV(j-1) [vf=V(j-1), P[(j-1)&1]]
    for (int j = 1; j < n; ++j) {
        QKT(s, kf);
        PVACC((j - 1) & 1, vf);
        LOADV(vf, j);                              // V(j) for next iter's PV
        const int jn = (j + 1 < n) ? j + 1 : n - 1;
        LOADK(kf, jn);                             // K(j+1), clamped in-bounds
        EXPP(s, j, j & 1);
    }

    // Tail: PV(n-1)
    PVACC((n - 1) & 1, vf);

#undef LOADK
#undef LOADV
#undef QKT
#undef EXPP
#undef PVACC

    float inv[4];
    #pragma unroll
    for (int rg = 0; rg < 4; rg++) {
        float l = lsum[rg];
        l += __shfl_xor(l, 1);
        l += __shfl_xor(l, 2);
        l += __shfl_xor(l, 4);
        l += __shfl_xor(l, 8);
        inv[rg] = 1.f / l;
    }
    #pragma unroll
    for (int nf = 0; nf < 4; nf++)
        #pragma unroll
        for (int rg = 0; rg < 4; rg++)
            out[(size_t)(qr0 + lg * 4 + rg) * HH + nf * 16 + l15] =
                accO[nf][rg] * inv[rg];
}

extern "C" void kernel_launch(void* const* d_in, const int* in_sizes, int n_in,
                              void* d_out, int out_size, void* d_ws, size_t ws_size,
                              hipStream_t stream) {
    const float* x  = (const float*)d_in[0];
    const float* Wq = (const float*)d_in[1];
    const float* bq = (const float*)d_in[2];
    const float* Wk = (const float*)d_in[3];
    const float* bk = (const float*)d_in[4];
    const float* Wv = (const float*)d_in[5];
    const float* bv = (const float*)d_in[6];
    float* out = (float*)d_out;

    unsigned short* qb = (unsigned short*)d_ws;        // [M][64] bf16 (pre-scaled)
    unsigned short* kb = qb + (size_t)MM * HH;         // [M][64] bf16
    unsigned short* vt = kb + (size_t)MM * HH;         // [B][64][512] bf16
    unsigned short* Wt = vt + (size_t)MM * HH;         // [192][384] bf16

    prep_w<<<dim3(18), dim3(256), 0, stream>>>(Wq, Wk, Wv, Wt);
    qkv_proj_mfma<<<dim3(MM / 32), dim3(256), 0, stream>>>(
        x, Wt, bq, bk, bv, qb, kb, vt);
    attn_mfma<<<dim3(2048), dim3(64), 0, stream>>>(qb, kb, vt, out);
}

// Round 6
// 51.771 us; speedup vs baseline: 1.1055x; 1.1055x over previous
//
#include <hip/hip_runtime.h>
#include <math.h>

#define BB 64
#define TT 512
#define CC 384
#define HH 64
#define MM (BB*TT)   // 32768 rows

// 0.125 (H^-0.5) * log2(e): scores hit hw exp2 directly; exp2(s*0.125*log2e)==exp(s*0.125)
#define QSCALE 0.18033688011112042f

typedef __attribute__((ext_vector_type(8))) short short8;
typedef __attribute__((ext_vector_type(4))) float f32x4;

__device__ __forceinline__ unsigned short f2bf(float f) {
    union { float f; unsigned int u; } x; x.f = f;
    unsigned int r = x.u + 0x7fff + ((x.u >> 16) & 1);   // RNE
    return (unsigned short)(r >> 16);
}

// ---------------- Kernel 0: W transpose + bf16 convert ----------------
// Wt[192][384] bf16: rows = output col n (0..63 Q, 64..127 K, 128..191 V).
// Q part pre-scaled by QSCALE.
__global__ __launch_bounds__(256) void prep_w(
    const float* __restrict__ Wq, const float* __restrict__ Wk,
    const float* __restrict__ Wv, unsigned short* __restrict__ Wt)
{
    __shared__ float t[64][65];
    const int which = blockIdx.x / 6;
    const int kt    = blockIdx.x % 6;
    const float* W = (which == 0) ? Wq : (which == 1) ? Wk : Wv;
    const float sc = (which == 0) ? QSCALE : 1.f;
    const int tid = threadIdx.x;
    #pragma unroll
    for (int i = 0; i < 16; i++) {
        int idx = tid + i * 256;
        int kl = idx >> 6, n = idx & 63;
        t[kl][n] = W[(size_t)(kt * 64 + kl) * HH + n];
    }
    __syncthreads();
    #pragma unroll
    for (int i = 0; i < 16; i++) {
        int idx = tid + i * 256;
        int nl = idx >> 6, kl = idx & 63;
        Wt[(size_t)(which * 64 + nl) * CC + kt * 64 + kl] = f2bf(t[kl][nl] * sc);
    }
}

// ---------------- Kernel 1: fused QKV projection via bf16 MFMA (64-row tiles) ----------------
// Round-4 version (best so far): 512 blocks, q/k epilogue via LDS -> packed 16B stores.
__global__ __launch_bounds__(256) void qkv_proj_mfma(
    const float* __restrict__ x, const unsigned short* __restrict__ Wt,
    const float* __restrict__ bq, const float* __restrict__ bk,
    const float* __restrict__ bv,
    unsigned short* __restrict__ qb, unsigned short* __restrict__ kb,
    unsigned short* __restrict__ vt)
{
    __shared__ unsigned short xs[64][CC + 8];   // [64][392] bf16
    const int tid  = threadIdx.x;
    const int w    = tid >> 6;
    const int lane = tid & 63;
    const int l15  = lane & 15;
    const int lg   = lane >> 4;
    const int rows0 = blockIdx.x * 64;

    #pragma unroll
    for (int kc = 0; kc < 6; kc++) {
        #pragma unroll
        for (int i = 0; i < 4; i++) {
            int idx = tid + i * 256;
            int row = idx >> 4, j4 = idx & 15;
            const float4 xv = *reinterpret_cast<const float4*>(
                &x[(size_t)(rows0 + row) * CC + kc * 64 + j4 * 4]);
            ushort4 pk;
            pk.x = f2bf(xv.x); pk.y = f2bf(xv.y);
            pk.z = f2bf(xv.z); pk.w = f2bf(xv.w);
            *reinterpret_cast<ushort4*>(&xs[row][kc * 64 + j4 * 4]) = pk;
        }
    }
    __syncthreads();

    f32x4 acc[4][3];
    #pragma unroll
    for (int mi = 0; mi < 4; mi++)
        #pragma unroll
        for (int f = 0; f < 3; f++) acc[mi][f] = (f32x4){0.f, 0.f, 0.f, 0.f};

    #pragma unroll 4
    for (int ks = 0; ks < 12; ks++) {
        short8 afrag[4];
        #pragma unroll
        for (int mi = 0; mi < 4; mi++)
            afrag[mi] = *reinterpret_cast<const short8*>(
                &xs[mi * 16 + l15][ks * 32 + lg * 8]);
        #pragma unroll
        for (int f = 0; f < 3; f++) {
            const int n = w * 48 + f * 16 + l15;
            const short8 bfrag = *reinterpret_cast<const short8*>(
                &Wt[(size_t)n * CC + ks * 32 + lg * 8]);
            #pragma unroll
            for (int mi = 0; mi < 4; mi++)
                acc[mi][f] = __builtin_amdgcn_mfma_f32_16x16x32_bf16(
                    afrag[mi], bfrag, acc[mi][f], 0, 0, 0);
        }
    }

    // ---- epilogue. D: col = lane&15, row = (lane>>4)*4 + reg ----
    const int batch = rows0 >> 9;
    const int t0    = rows0 & 511;

    __syncthreads();   // all A-frag reads of xs done; reuse as transpose tile
    unsigned short (*L)[72] = reinterpret_cast<unsigned short (*)[72]>(&xs[0][0]);

    #pragma unroll
    for (int f = 0; f < 3; f++) {
        const int c = w * 48 + f * 16 + l15;   // 0..191
        if (c < 64) {
            const float bb = bq[c] * QSCALE;
            #pragma unroll
            for (int mi = 0; mi < 4; mi++)
                #pragma unroll
                for (int rr = 0; rr < 4; rr++)
                    L[mi * 16 + lg * 4 + rr][c] = f2bf(acc[mi][f][rr] + bb);
        } else if (c < 128) {
            const int ci = c - 64;
            const float bb = bk[ci];
            #pragma unroll
            for (int mi = 0; mi < 4; mi++)
                #pragma unroll
                for (int rr = 0; rr < 4; rr++)
                    L[64 + mi * 16 + lg * 4 + rr][ci] = f2bf(acc[mi][f][rr] + bb);
        } else {
            const int ci = c - 128;
            const float bb = bv[ci];
            #pragma unroll
            for (int mi = 0; mi < 4; mi++) {
                ushort4 pk;
                pk.x = f2bf(acc[mi][f][0] + bb);
                pk.y = f2bf(acc[mi][f][1] + bb);
                pk.z = f2bf(acc[mi][f][2] + bb);
                pk.w = f2bf(acc[mi][f][3] + bb);
                *reinterpret_cast<ushort4*>(
                    &vt[((size_t)batch * HH + ci) * TT + t0 + mi * 16 + lg * 4]) = pk;
            }
        }
    }
    __syncthreads();

    #pragma unroll
    for (int i = 0; i < 4; i++) {
        int idx = tid + i * 256;          // 0..1023
        int r = idx >> 3, c8 = idx & 7;
        const short8 val = *reinterpret_cast<const short8*>(&L[r][c8 * 8]);
        if (r < 64)
            *reinterpret_cast<short8*>(&qb[(size_t)(rows0 + r) * HH + c8 * 8]) = val;
        else
            *reinterpret_cast<short8*>(&kb[(size_t)(rows0 + r - 64) * HH + c8 * 8]) = val;
    }
}

// ---------------- Kernel 2: MFMA flash attention, 4-way split-K ----------------
// Block = (b, qs), 256 threads = 4 waves. Wave w handles KV tiles j == w (mod 4)
// with private unnormalized accO/lsum (fixed-max softmax -> linear combine).
// Cuts the longest serial chain 4x (8 -> 2 tile-steps/wave) and raises
// occupancy to ~12 waves/CU. Combine once at the end through LDS.
__global__ __launch_bounds__(256, 3) void attn_mfma(
    const unsigned short* __restrict__ q, const unsigned short* __restrict__ k,
    const unsigned short* __restrict__ vt, float* __restrict__ out)
{
    __shared__ float Cmb[4][16][68];            // 17.4 KB partial accO
    __shared__ float Ls[4][16];                 // per-wave row sums
    __shared__ unsigned short P[4][16][72];     // per-wave P strip, 9.2 KB
    const int tid  = threadIdx.x;
    const int w    = tid >> 6;
    const int lane = tid & 63;
    const int l15  = lane & 15;
    const int lg   = lane >> 4;
    const int qs   = blockIdx.x >> 6;       // 0..31
    const int b    = blockIdx.x & 63;
    const int qr0  = b * TT + qs * 16;
    const int n    = (qs >> 2) + 1;         // KV tiles for this strip

    const unsigned short* __restrict__ kbase = k  + (size_t)b * TT * HH;
    const unsigned short* __restrict__ vbase = vt + (size_t)b * HH * TT;

    short8 aq[2];
    #pragma unroll
    for (int ks = 0; ks < 2; ks++)
        aq[ks] = *reinterpret_cast<const short8*>(
            &q[(size_t)(qr0 + l15) * HH + ks * 32 + lg * 8]);

    f32x4 accO[4];
    #pragma unroll
    for (int nf = 0; nf < 4; nf++) accO[nf] = (f32x4){0.f, 0.f, 0.f, 0.f};
    float lsum[4] = {0.f, 0.f, 0.f, 0.f};

    for (int j = w; j < n; j += 4) {
        // K fragments + QK^T
        short8 kf[2][4];
        #pragma unroll
        for (int ks = 0; ks < 2; ks++)
            #pragma unroll
            for (int nf = 0; nf < 4; nf++)
                kf[ks][nf] = *reinterpret_cast<const short8*>(
                    &kbase[(size_t)(j * 64 + nf * 16 + l15) * HH + ks * 32 + lg * 8]);
        f32x4 s[4];
        #pragma unroll
        for (int nf = 0; nf < 4; nf++) s[nf] = (f32x4){0.f, 0.f, 0.f, 0.f};
        #pragma unroll
        for (int ks = 0; ks < 2; ks++)
            #pragma unroll
            for (int nf = 0; nf < 4; nf++)
                s[nf] = __builtin_amdgcn_mfma_f32_16x16x32_bf16(
                    aq[ks], kf[ks][nf], s[nf], 0, 0, 0);

        // V fragments (issued before exp; latency hides under VALU)
        short8 vf[2][4];
        #pragma unroll
        for (int ks = 0; ks < 2; ks++)
            #pragma unroll
            for (int nf = 0; nf < 4; nf++)
                vf[ks][nf] = *reinterpret_cast<const short8*>(
                    &vbase[(size_t)(nf * 16 + l15) * TT + j * 64 + ks * 32 + lg * 8]);

        // fixed-max softmax numerator; C-layout row = lg*4+rg, col = nf*16+l15
        float p[4][4];
        if (j == n - 1) {
            #pragma unroll
            for (int nf = 0; nf < 4; nf++)
                #pragma unroll
                for (int rg = 0; rg < 4; rg++)
                    p[nf][rg] = (j * 64 + nf * 16 + l15 > qs * 16 + lg * 4 + rg)
                                ? 0.f : exp2f(s[nf][rg]);
        } else {
            #pragma unroll
            for (int nf = 0; nf < 4; nf++)
                #pragma unroll
                for (int rg = 0; rg < 4; rg++)
                    p[nf][rg] = exp2f(s[nf][rg]);
        }
        #pragma unroll
        for (int rg = 0; rg < 4; rg++)
            lsum[rg] += (p[0][rg] + p[1][rg]) + (p[2][rg] + p[3][rg]);

        // P -> bf16 LDS (wave-local strip, in-order LDS pipe: no barrier)
        #pragma unroll
        for (int nf = 0; nf < 4; nf++)
            #pragma unroll
            for (int rg = 0; rg < 4; rg++)
                P[w][lg * 4 + rg][nf * 16 + l15] = f2bf(p[nf][rg]);

        // PV
        #pragma unroll
        for (int ks = 0; ks < 2; ks++) {
            const short8 pa = *reinterpret_cast<const short8*>(
                &P[w][l15][ks * 32 + lg * 8]);
            #pragma unroll
            for (int nf = 0; nf < 4; nf++)
                accO[nf] = __builtin_amdgcn_mfma_f32_16x16x32_bf16(
                    pa, vf[ks][nf], accO[nf], 0, 0, 0);
        }
    }

    // ---- publish partials ----
    #pragma unroll
    for (int rg = 0; rg < 4; rg++) {
        float l = lsum[rg];
        l += __shfl_xor(l, 1);
        l += __shfl_xor(l, 2);
        l += __shfl_xor(l, 4);
        l += __shfl_xor(l, 8);
        if (l15 == 0) Ls[w][lg * 4 + rg] = l;
    }
    #pragma unroll
    for (int nf = 0; nf < 4; nf++)
        #pragma unroll
        for (int rg = 0; rg < 4; rg++)
            Cmb[w][lg * 4 + rg][nf * 16 + l15] = accO[nf][rg];
    __syncthreads();

    // ---- combine: wave w owns output columns [w*16, w*16+16) ----
    #pragma unroll
    for (int rg = 0; rg < 4; rg++) {
        const int row = lg * 4 + rg;
        const float ltot = Ls[0][row] + Ls[1][row] + Ls[2][row] + Ls[3][row];
        const float sum = Cmb[0][row][w * 16 + l15] + Cmb[1][row][w * 16 + l15]
                        + Cmb[2][row][w * 16 + l15] + Cmb[3][row][w * 16 + l15];
        out[(size_t)(qr0 + row) * HH + w * 16 + l15] = sum / ltot;
    }
}

extern "C" void kernel_launch(void* const* d_in, const int* in_sizes, int n_in,
                              void* d_out, int out_size, void* d_ws, size_t ws_size,
                              hipStream_t stream) {
    const float* x  = (const float*)d_in[0];
    const float* Wq = (const float*)d_in[1];
    const float* bq = (const float*)d_in[2];
    const float* Wk = (const float*)d_in[3];
    const float* bk = (const float*)d_in[4];
    const float* Wv = (const float*)d_in[5];
    const float* bv = (const float*)d_in[6];
    float* out = (float*)d_out;

    unsigned short* qb = (unsigned short*)d_ws;        // [M][64] bf16 (pre-scaled)
    unsigned short* kb = qb + (size_t)MM * HH;         // [M][64] bf16
    unsigned short* vt = kb + (size_t)MM * HH;         // [B][64][512] bf16
    unsigned short* Wt = vt + (size_t)MM * HH;         // [192][384] bf16

    prep_w<<<dim3(18), dim3(256), 0, stream>>>(Wq, Wk, Wv, Wt);
    qkv_proj_mfma<<<dim3(MM / 64), dim3(256), 0, stream>>>(
        x, Wt, bq, bk, bv, qb, kb, vt);
    attn_mfma<<<dim3(2048), dim3(256), 0, stream>>>(qb, kb, vt, out);
}